// Round 3
// 5393.980 us; speedup vs baseline: 1.9820x; 1.9820x over previous
//
#include <hip/hip_runtime.h>
#include <hip/hip_bf16.h>

typedef __hip_bfloat16 bf16;
typedef unsigned long long ull;
typedef __attribute__((ext_vector_type(8))) short s16x8;
typedef __attribute__((ext_vector_type(4))) float f32x4;

#define B_      64
#define NMAX_   299
#define N_      300
#define D_      512
#define H_      512
#define NHEADS_ 8
#define NHID_   64
#define SCLD    304                  // padded leading dim for (n,m) score rows
#define SCSZ    (N_ * SCLD)          // 91,200 floats per batch
#define LDP     48                   // padded LDS row stride (bf16 elems) for mgemm

// ---------------------------------------------------------------- utilities

__device__ __forceinline__ float sigmoidf_(float x) { return 1.0f / (1.0f + expf(-x)); }

// ---------------------------------------------------------------- embedding
// writes bf16 directly: embx feeds only the MFMA projections.

__global__ void embed_k(const int* __restrict__ tokens, const int* __restrict__ tok_lens,
                        const int* __restrict__ seq_lens, const float* __restrict__ emb,
                        bf16* __restrict__ out)
{
    const int n = blockIdx.x, b = blockIdx.y;
    const int d = threadIdx.x * 4;
    const int nc = seq_lens[b] - 1;
    float4 v;
    if (n < nc) {
        const int tl = tok_lens[b * NMAX_ + n];
        const int* tp = tokens + (b * NMAX_ + n) * 8;
        float4 acc = {0.f, 0.f, 0.f, 0.f};
        for (int t = 0; t < 8; ++t) {
            if (t < tl) {
                const float4 e = *(const float4*)(emb + (long)tp[t] * D_ + d);
                acc.x += e.x; acc.y += e.y; acc.z += e.z; acc.w += e.w;
            }
        }
        const float inv = 1.0f / (float)nc;
        v.x = acc.x * inv; v.y = acc.y * inv; v.z = acc.z * inv; v.w = acc.w * inv;
    } else {
        const int row = (n == nc) ? 2 : 0;
        v = *(const float4*)(emb + row * D_ + d);
    }
    bf16 o[4] = {__float2bfloat16(v.x), __float2bfloat16(v.y),
                 __float2bfloat16(v.z), __float2bfloat16(v.w)};
    *(uint2*)(out + ((long)b * N_ + n) * D_ + d) = *(uint2*)o;
}

// ------------------------------------------------------------------- cond

__global__ void cond_k(const float* __restrict__ adj, unsigned char* __restrict__ cond)
{
    __shared__ float T1[64][65];
    __shared__ float T2[64][65];
    const int b = blockIdx.z;
    const int n0 = blockIdx.x * 64, m0 = blockIdx.y * 64;
    const int jj = threadIdx.x & 63, i0 = threadIdx.x >> 6;
    for (int r = 0; r < 16; ++r) {
        const int i = i0 * 16 + r;
        const int n = n0 + i, m = m0 + jj;
        T1[i][jj] = (n < N_ && m < N_) ? adj[((long)b * N_ + n) * N_ + m] : 0.f;
        const int n2 = m0 + i, m2 = n0 + jj;
        T2[i][jj] = (n2 < N_ && m2 < N_) ? adj[((long)b * N_ + n2) * N_ + m2] : 0.f;
    }
    __syncthreads();
    for (int r = 0; r < 16; ++r) {
        const int i = i0 * 16 + r;
        const int n = n0 + i, m = m0 + jj;
        if (n < N_ && m < N_) {
            const float v = T1[i][jj] + T2[jj][i] + ((n == m) ? 1.f : 0.f);
            cond[((long)b * N_ + n) * N_ + m] = (v > 0.f) ? 1 : 0;
        }
    }
}

// -------------------------------------------------- weight prep (fp32->bf16)

__global__ void wgath_k(const float* __restrict__ W, bf16* __restrict__ out)
{   // (8,512,64) -> (512,512): out[h*64+o][d] = W[h][d][o]
    const int row = blockIdx.x;
    const int d = threadIdx.x;
    const int h = row >> 6, o = row & 63;
    out[row * 512 + d] = __float2bfloat16(W[((long)h * 512 + d) * 64 + o]);
}

__global__ void wtr_k(const float* __restrict__ W, bf16* __restrict__ out)
{   // (512,512) -> transposed: out[o][i] = W[i][o]
    const int o = blockIdx.x;
    const int i = threadIdx.x;
    out[o * 512 + i] = __float2bfloat16(W[(long)i * 512 + o]);
}

__global__ void f2b_k(const float* __restrict__ in, bf16* __restrict__ out, long n)
{
    for (long i = (long)blockIdx.x * 256 + threadIdx.x; i < n; i += (long)gridDim.x * 256)
        out[i] = __float2bfloat16(in[i]);
}

// ------------------------------------------------------- bf16 MFMA GEMM
// C[m][n] = sum_k A[m][k] * B[n][k]   (B transposed, row-major [N][K]).
// 4 waves/block; each wave owns a (BM/2)x(BN/2) quadrant of 16x16x32 frags.
// K must be a multiple of 32. Bounds-guarded on M and N (zeros staged OOB).

template<int BM, int BN, bool OBF>
__global__ __launch_bounds__(256) void mgemm_k(
    const bf16* __restrict__ A, long sA, int lda,
    const bf16* __restrict__ Bm, long sB, int ldb,
    void* __restrict__ C, long sC, int ldc,
    int M, int N, int K)
{
    __shared__ short As[BM * LDP];
    __shared__ short Bs[BN * LDP];
    const int z = blockIdx.z;
    const bf16* Ab = A + (long)z * sA;
    const bf16* Bb = Bm + (long)z * sB;
    const int m0 = blockIdx.x * BM, n0 = blockIdx.y * BN;
    const int tid = threadIdx.x;
    const int lane = tid & 63;
    const int w = tid >> 6;
    const int wm = (w >> 1) * (BM / 2);
    const int wn = (w & 1) * (BN / 2);
    constexpr int MR = BM / 32;
    constexpr int NR = BN / 32;
    f32x4 acc[MR][NR] = {};

    const int srow = tid >> 2;           // staging row 0..63
    const int sslot = (tid & 3) * 8;     // bf16 offset within 32-wide k-slab

    for (int k0 = 0; k0 < K; k0 += 32) {
        #pragma unroll
        for (int r = 0; r < BM / 64; ++r) {
            const int row = r * 64 + srow;
            uint4 v = {0u, 0u, 0u, 0u};
            if (m0 + row < M)
                v = *(const uint4*)(Ab + (long)(m0 + row) * lda + k0 + sslot);
            *(uint4*)&As[row * LDP + sslot] = v;
        }
        #pragma unroll
        for (int r = 0; r < BN / 64; ++r) {
            const int row = r * 64 + srow;
            uint4 v = {0u, 0u, 0u, 0u};
            if (n0 + row < N)
                v = *(const uint4*)(Bb + (long)(n0 + row) * ldb + k0 + sslot);
            *(uint4*)&Bs[row * LDP + sslot] = v;
        }
        __syncthreads();
        s16x8 aq[MR], bq[NR];
        #pragma unroll
        for (int i = 0; i < MR; ++i)
            aq[i] = *(const s16x8*)&As[(wm + i * 16 + (lane & 15)) * LDP + (lane >> 4) * 8];
        #pragma unroll
        for (int j = 0; j < NR; ++j)
            bq[j] = *(const s16x8*)&Bs[(wn + j * 16 + (lane & 15)) * LDP + (lane >> 4) * 8];
        #pragma unroll
        for (int i = 0; i < MR; ++i)
            #pragma unroll
            for (int j = 0; j < NR; ++j)
                acc[i][j] = __builtin_amdgcn_mfma_f32_16x16x32_bf16(aq[i], bq[j], acc[i][j], 0, 0, 0);
        __syncthreads();
    }

    // C/D layout: col = lane&15, row = (lane>>4)*4 + reg  (m89-verified)
    #pragma unroll
    for (int i = 0; i < MR; ++i) {
        const int mrow = m0 + wm + i * 16 + (lane >> 4) * 4;
        #pragma unroll
        for (int j = 0; j < NR; ++j) {
            const int ncol = n0 + wn + j * 16 + (lane & 15);
            if (ncol < N) {
                #pragma unroll
                for (int e = 0; e < 4; ++e) {
                    const int mm = mrow + e;
                    if (mm < M) {
                        const long idx = (long)z * sC + (long)mm * ldc + ncol;
                        if (OBF) ((bf16*)C)[idx] = __float2bfloat16(acc[i][j][e]);
                        else     ((float*)C)[idx] = acc[i][j][e];
                    }
                }
            }
        }
    }
}

// ------------------------------------------------------- generic fp32 GEMM
// leftovers only: layer-1 scores (K=64), hp1, hp2 (bf16 B via BBF).

template<bool BT, bool OBF, bool BBF = false>
__global__ __launch_bounds__(256) void gemm_k(
    const float* __restrict__ A, long sA, int lda,
    const float* __restrict__ B, long sB, int ldb,
    void* __restrict__ C, long sC, int ldc,
    int M, int N, int K)
{
    __shared__ alignas(16) float As[16][64];
    __shared__ alignas(16) float Bs[16][64];
    const int z = blockIdx.z;
    const float* Ab = A + (long)z * sA;
    const float* Bb = B + (long)z * sB;
    const int m0 = blockIdx.x * 64, n0 = blockIdx.y * 64;
    const int tid = threadIdx.x;
    const int tx = tid & 15, ty = tid >> 4;
    const int amm = tid >> 2, ak4 = (tid & 3) * 4;
    float acc[4][4] = {};

    for (int k0 = 0; k0 < K; k0 += 16) {
        {
            float4 v = {0.f, 0.f, 0.f, 0.f};
            const int row = m0 + amm;
            if (row < M) {
                if (k0 + ak4 + 3 < K) {
                    v = *(const float4*)(Ab + (long)row * lda + k0 + ak4);
                } else {
                    float* vp = (float*)&v;
                    for (int j = 0; j < 4; ++j)
                        if (k0 + ak4 + j < K) vp[j] = Ab[(long)row * lda + k0 + ak4 + j];
                }
            }
            As[ak4 + 0][amm] = v.x; As[ak4 + 1][amm] = v.y;
            As[ak4 + 2][amm] = v.z; As[ak4 + 3][amm] = v.w;
        }
        if (BT) {
            float4 v = {0.f, 0.f, 0.f, 0.f};
            const int row = n0 + amm;
            if (row < N) {
                if (k0 + ak4 + 3 < K) {
                    v = *(const float4*)(Bb + (long)row * ldb + k0 + ak4);
                } else {
                    float* vp = (float*)&v;
                    for (int j = 0; j < 4; ++j)
                        if (k0 + ak4 + j < K) vp[j] = Bb[(long)row * ldb + k0 + ak4 + j];
                }
            }
            Bs[ak4 + 0][amm] = v.x; Bs[ak4 + 1][amm] = v.y;
            Bs[ak4 + 2][amm] = v.z; Bs[ak4 + 3][amm] = v.w;
        } else {
            const int nn = tid & 63, kb = tid >> 6;
            #pragma unroll
            for (int r = 0; r < 4; ++r) {
                const int kk = kb * 4 + r;
                float v = 0.f;
                if (k0 + kk < K && n0 + nn < N) {
                    if (BBF) v = __bfloat162float(
                        ((const bf16*)B)[(long)z * sB + (long)(k0 + kk) * ldb + n0 + nn]);
                    else v = Bb[(long)(k0 + kk) * ldb + n0 + nn];
                }
                Bs[kk][nn] = v;
            }
        }
        __syncthreads();
        #pragma unroll
        for (int kk = 0; kk < 16; ++kk) {
            const float4 av = *(const float4*)&As[kk][ty * 4];
            const float4 bv = *(const float4*)&Bs[kk][tx * 4];
            const float* ap = (const float*)&av;
            const float* bp = (const float*)&bv;
            #pragma unroll
            for (int i = 0; i < 4; ++i)
                #pragma unroll
                for (int j = 0; j < 4; ++j)
                    acc[i][j] = fmaf(ap[i], bp[j], acc[i][j]);
        }
        __syncthreads();
    }
    for (int i = 0; i < 4; ++i) {
        const int m = m0 + ty * 4 + i;
        if (m >= M) break;
        for (int j = 0; j < 4; ++j) {
            const int nn = n0 + tx * 4 + j;
            if (nn < N) {
                const long idx = (long)z * sC + (long)m * ldc + nn;
                if (OBF) ((bf16*)C)[idx] = __float2bfloat16(acc[i][j]);
                else     ((float*)C)[idx] = acc[i][j];
            }
        }
    }
}

// ------------------------------------------------- softmaxes for GAT layer

__global__ void bsoft_k(const float* __restrict__ sc, float* __restrict__ mx, float* __restrict__ sm)
{
    const int idx = blockIdx.x * 256 + threadIdx.x;
    if (idx >= SCSZ) return;
    float m = -1e30f;
    for (int b = 0; b < B_; ++b) m = fmaxf(m, sc[(long)b * SCSZ + idx]);
    float s = 0.f;
    for (int b = 0; b < B_; ++b) s += expf(sc[(long)b * SCSZ + idx] - m);
    mx[idx] = m; sm[idx] = s;
}

// column softmax, n-parallel: 512 threads = 64 columns x 8 n-strips,
// LDS tree-reduce for per-column max/sum (was 128-thr, 3x serial 300-walks).
__global__ __launch_bounds__(512) void colsoft_k(
    float* __restrict__ sc, const float* __restrict__ mx,
    const float* __restrict__ sm, const unsigned char* __restrict__ cond)
{
    __shared__ float red[8][64];
    const int ml = threadIdx.x & 63;
    const int ng = threadIdx.x >> 6;      // 0..7
    const int m = blockIdx.x * 64 + ml;
    const int b = blockIdx.y;
    float* scb = sc + (long)b * SCSZ;
    const unsigned char* cb = cond + (long)b * (N_ * N_);
    const bool act = m < N_;

    float vmax = -1e30f;
    for (int n = ng; n < N_; n += 8) {
        const int o = n * SCLD + m;
        if (act && cb[n * N_ + m]) {
            const float e = expf(scb[o] - mx[o]) / sm[o];
            scb[o] = e;
            vmax = fmaxf(vmax, e);
        }
    }
    red[ng][ml] = vmax;
    __syncthreads();
    vmax = red[0][ml];
    #pragma unroll
    for (int i = 1; i < 8; ++i) vmax = fmaxf(vmax, red[i][ml]);

    float ssum = 0.f;
    for (int n = ng; n < N_; n += 8) {
        const int o = n * SCLD + m;
        if (act && cb[n * N_ + m]) ssum += expf(scb[o] - vmax);
    }
    __syncthreads();
    red[ng][ml] = ssum;
    __syncthreads();
    ssum = 0.f;
    #pragma unroll
    for (int i = 0; i < 8; ++i) ssum += red[i][ml];
    const float inv = 1.0f / ssum;

    for (int n = ng; n < N_; n += 8) {
        const int o = n * SCLD + m;
        if (act) scb[o] = cb[n * N_ + m] ? expf(scb[o] - vmax) * inv : 0.f;
    }
}

__global__ void nsoft_k(const float* __restrict__ hp, bf16* __restrict__ out)
{
    const int f = blockIdx.x * 256 + threadIdx.x;  // 0..511
    const int b = blockIdx.y;
    const float* hb = hp + (long)b * (N_ * 512) + f;
    float vmax = -1e30f;
    for (int n = 0; n < N_; ++n) vmax = fmaxf(vmax, hb[n * 512]);
    float s = 0.f;
    for (int n = 0; n < N_; ++n) s += expf(hb[n * 512] - vmax);
    const float inv = 1.0f / s;
    bf16* ob = out + (long)b * (N_ * 512) + f;
    for (int n = 0; n < N_; ++n) ob[n * 512] = __float2bfloat16(expf(hb[n * 512] - vmax) * inv);
}

// ----------------------------------------------------------------- GRU prep

__global__ void xrev_k(const bf16* __restrict__ out2, const int* __restrict__ seq_lens,
                       bf16* __restrict__ xr)
{
    const int t = blockIdx.x, b = blockIdx.y;
    const int d = threadIdx.x * 4;
    int src = seq_lens[b] - 1 - t;
    if (src < 0) src = 0;
    *(uint2*)(xr + ((long)t * B_ + b) * 512 + d) =
        *(const uint2*)(out2 + ((long)b * N_ + src) * 512 + d);
}

__global__ void zero_k(float* __restrict__ p, long n)
{
    for (long i = (long)blockIdx.x * 256 + threadIdx.x; i < n; i += (long)gridDim.x * 256)
        p[i] = 0.f;
}

// ------------------------------------------------------ GRU recurrence
// 256 blocks x 512 threads -> ALL 256 CUs. Block = (dir, 8 u's, 32 batches).
// Whh slab (48 KB) LDS-resident; h staged via relaxed agent-scope atomics
// into double-buffered 16-KB quarter bufs. LDS 81 KB -> 1 block/CU.

__device__ __forceinline__ void dbar(unsigned* __restrict__ gc, unsigned* __restrict__ root,
                                     int step) {
    __syncthreads();
    if (threadIdx.x == 0) {
        const unsigned old =
            __hip_atomic_fetch_add(gc, 1u, __ATOMIC_RELAXED, __HIP_MEMORY_SCOPE_AGENT);
        if (old == (unsigned)(step * 8 + 7))
            __hip_atomic_fetch_add(root, 1u, __ATOMIC_RELAXED, __HIP_MEMORY_SCOPE_AGENT);
        while (__hip_atomic_load(root, __ATOMIC_RELAXED, __HIP_MEMORY_SCOPE_AGENT)
               < (unsigned)((step + 1) * 16)) {
            __builtin_amdgcn_s_sleep(1);
        }
    }
    __syncthreads();
}

__global__ __launch_bounds__(512, 1) void gru_recur(
    const bf16* __restrict__ gif, const bf16* __restrict__ gib,
    const float* __restrict__ Whh, const float* __restrict__ bih,
    const float* __restrict__ bhh, const int* __restrict__ seq_lens,
    float* __restrict__ hbuf, unsigned* __restrict__ bar,
    float* __restrict__ outf, float* __restrict__ outb)
{
    __shared__ alignas(16) float hs[2][4096];
    __shared__ alignas(16) float wlds[12352];
    const int tid = threadIdx.x;
    const int b32 = tid & 31;
    const int kh  = (tid >> 5) & 1;
    const int w = __builtin_amdgcn_readfirstlane(tid >> 6);
    const int dir = blockIdx.x >> 7;
    const int bl  = blockIdx.x & 127;
    const int ub  = (bl >> 1) * 8;
    const int bh  = bl & 1;
    const int u   = ub + w;
    const int b   = bh * 32 + b32;
    const int grp = bl >> 3;
    unsigned* gc   = bar + (dir * 16 + grp) * 32;
    unsigned* root = bar + 1024 + dir * 32;

    {
        const float* Wbase = Whh + (long)dir * (1536 * 512);
        #pragma unroll
        for (int it = 0; it < 6; ++it) {
            const int idx = tid + it * 512;
            const int row = idx >> 7;
            const int kc  = idx & 127;
            const int ul = row / 3, g = row % 3;
            const float4 v = *(const float4*)(Wbase + (long)(g * 512 + ub + ul) * 512 + kc * 4);
            *(float4*)(wlds + ul * 1536 + g * 512 + kc * 4) = v;
        }
    }
    const float* wl = wlds + w * 1536;

    const bf16* gi = dir ? gib : gif;
    const float cr = bih[dir * 1536 + u];
    const float cz = bih[dir * 1536 + 512 + u];
    const float cn = bih[dir * 1536 + 1024 + u];
    const float br = bhh[dir * 1536 + u];
    const float bz = bhh[dir * 1536 + 512 + u];
    const float bn = bhh[dir * 1536 + 1024 + u];
    const int sl = seq_lens[b];

    if (tid < 256)
        __hip_atomic_store(&hbuf[dir * 32768 + u * 64 + b], 0.0f,
                           __ATOMIC_RELAXED, __HIP_MEMORY_SCOPE_AGENT);
    dbar(gc, root, 0);

    for (int t = 0; t < N_; ++t) {
        const float* hc = hbuf + ((t & 1) ? 65536 : 0) + dir * 32768;
        float* hn       = hbuf + ((t & 1) ? 0 : 65536) + dir * 32768;
        const ull* hc8 = (const ull*)hc;

        const long gbase = (long)t * 98304 + (long)u * 64 + b;
        const float gr0 = __bfloat162float(gi[gbase]);
        const float gz0 = __bfloat162float(gi[gbase + 32768]);
        const float gn0 = __bfloat162float(gi[gbase + 65536]);

        ull r[4];
        #pragma unroll
        for (int i = 0; i < 4; ++i) {
            const int x = i * 512 + tid;
            const int k = x >> 4, j = x & 15;
            r[i] = __hip_atomic_load(hc8 + k * 32 + bh * 16 + j,
                                     __ATOMIC_RELAXED, __HIP_MEMORY_SCOPE_AGENT);
        }
        {
            ull* dst = (ull*)hs[0];
            #pragma unroll
            for (int i = 0; i < 4; ++i) dst[i * 512 + tid] = r[i];
        }

        float ar = 0.f, az = 0.f, an = 0.f, hprev = 0.f;
        for (int q = 0; q < 4; ++q) {
            __syncthreads();
            if (q < 3) {
                #pragma unroll
                for (int i = 0; i < 4; ++i) {
                    const int x = i * 512 + tid;
                    const int k = (q + 1) * 128 + (x >> 4), j = x & 15;
                    r[i] = __hip_atomic_load(hc8 + k * 32 + bh * 16 + j,
                                             __ATOMIC_RELAXED, __HIP_MEMORY_SCOPE_AGENT);
                }
            }
            const float* hq = hs[q & 1];
            const float* wr = wl + q * 128 + kh * 64;
            const float* wz = wr + 512;
            const float* wn = wr + 1024;
            const float* hb = hq + kh * 64 * 32 + b32;
            #pragma unroll 8
            for (int kk = 0; kk < 64; ++kk) {
                const float hk = hb[kk * 32];
                ar = fmaf(hk, wr[kk], ar);
                az = fmaf(hk, wz[kk], az);
                an = fmaf(hk, wn[kk], an);
            }
            if (q == (u >> 7)) hprev = hq[(u & 127) * 32 + b32];
            if (q < 3) {
                ull* dst = (ull*)hs[(q + 1) & 1];
                #pragma unroll
                for (int i = 0; i < 4; ++i) dst[i * 512 + tid] = r[i];
            }
        }
        ar += __shfl_xor(ar, 32);
        az += __shfl_xor(az, 32);
        an += __shfl_xor(an, 32);

        const float rg = sigmoidf_(cr + gr0 + br + ar);
        const float zg = sigmoidf_(cz + gz0 + bz + az);
        const float ng = tanhf(cn + gn0 + rg * (bn + an));
        const float hnew = (1.f - zg) * ng + zg * hprev;
        const bool msk = t < sl;
        if (kh == 0) {
            __hip_atomic_store(&hn[u * 64 + b], msk ? hnew : hprev,
                               __ATOMIC_RELAXED, __HIP_MEMORY_SCOPE_AGENT);
            if (dir == 0) {
                outf[(long)t * 32768 + u * 64 + b] = msk ? hnew : 0.f;
            } else if (msk) {
                outb[(long)(sl - 1 - t) * 32768 + u * 64 + b] = hnew;
            }
        }
        dbar(gc, root, t + 1);
    }
}

// --------------------------------------------------------------- finalize

__global__ void final_k(const float* __restrict__ outf, const float* __restrict__ outb,
                        const float* __restrict__ hbuf, const int* __restrict__ seq_lens,
                        float* __restrict__ dout)
{
    const long i = (long)blockIdx.x * 256 + threadIdx.x;
    const long NOUT = (long)N_ * B_ * 512;
    if (i < NOUT) {
        const int t = (int)(i >> 15);
        const int b = (int)((i >> 9) & 63);
        const int u = (int)(i & 511);
        const long src = (long)t * 32768 + u * 64 + b;
        dout[i] = (t < seq_lens[b]) ? outf[src] + outb[src] : 0.f;
    } else if (i < NOUT + 2 * B_ * 512) {
        const long j = i - NOUT;
        const int dir = (int)(j >> 15);
        const int b = (int)((j >> 9) & 63);
        const int u = (int)(j & 511);
        dout[i] = hbuf[dir * 32768 + u * 64 + b];
    }
}

__global__ void fail_zero_k(float* __restrict__ dout, long n)
{
    for (long i = (long)blockIdx.x * 256 + threadIdx.x; i < n; i += (long)gridDim.x * 256)
        dout[i] = 0.f;
}

// ----------------------------------------------------------------- launch

extern "C" void kernel_launch(void* const* d_in, const int* in_sizes, int n_in,
                              void* d_out, int out_size, void* d_ws, size_t ws_size,
                              hipStream_t stream)
{
    const int*   tokens   = (const int*)d_in[0];
    const int*   tok_lens = (const int*)d_in[1];
    const int*   seq_lens = (const int*)d_in[2];
    const float* adj      = (const float*)d_in[3];
    const float* emb      = (const float*)d_in[4];
    const float* Wq       = (const float*)d_in[5];
    const float* Wk       = (const float*)d_in[6];
    const float* Wq_o     = (const float*)d_in[7];
    const float* Wk_o     = (const float*)d_in[8];
    const float* gWih     = (const float*)d_in[9];
    const float* gWhh     = (const float*)d_in[10];
    const float* gbih     = (const float*)d_in[11];
    const float* gbhh     = (const float*)d_in[12];
    float* out = (float*)d_out;

    const long SZ = (long)B_ * N_ * 512;   // 9,830,400 elements
    // fp32 pool (3 slots) + bf16 pool (4 half-size slots) = 5*SZ floats total;
    // identical footprint to the previous 5-buffer layout, sc onward unchanged.
    float* F1 = (float*)d_ws;              // q1   -> outf
    float* F2 = F1 + SZ;                   // k1   -> outb
    float* F3 = F2 + SZ;                   // hp1  -> hp2
    bf16* b0 = (bf16*)(F3 + SZ);           // embx -> out2
    bf16* b1 = b0 + SZ;                    // x1   -> x_rev
    bf16* b2 = b1 + SZ;                    // q2   -> wih(bf16)
    bf16* b3 = b2 + SZ;                    // k2
    float* sc   = (float*)(b3 + SZ);       // == d_ws + 5*SZ, as before
    float* mx   = sc + (long)B_ * SCSZ;
    float* smv  = mx + SCSZ;
    unsigned char* cond = (unsigned char*)(smv + SCSZ);
    bf16* gif = (bf16*)(cond + (long)B_ * N_ * N_);
    bf16* gib = gif + (long)N_ * 1536 * B_;
    float* hbuf = (float*)(gib + (long)N_ * 1536 * B_);
    unsigned* bar = (unsigned*)(hbuf + 131072);
    const size_t needed = (size_t)((char*)(bar + 2048) - (char*)d_ws);
    if (ws_size < needed) {
        fail_zero_k<<<4096, 256, 0, stream>>>(out, out_size);
        return;
    }
    // transient bf16 weights live in regions dead at their use time
    bf16* wq1  = (bf16*)sc;                // consumed before sc first written
    bf16* wk1  = wq1 + 512 * 512;
    bf16* w2q  = (bf16*)sc;                // between layer-1 sc death and scores2
    bf16* w2k  = w2q + 512 * 512;
    bf16* wihb = b2;                       // q2 slot, dead after scores2

    // 1. layer-1 weight prep, embedding (bf16), cond
    wgath_k<<<512, 512, 0, stream>>>(Wq, wq1);
    wgath_k<<<512, 512, 0, stream>>>(Wk, wk1);
    embed_k<<<dim3(N_, B_), 128, 0, stream>>>(tokens, tok_lens, seq_lens, emb, b0);
    cond_k<<<dim3(5, 5, B_), 256, 0, stream>>>(adj, cond);

    // 2. layer-1 projections via MFMA (fp32 out): q1 -> F1, k1 -> F2
    mgemm_k<128, 128, false><<<dim3(150, 4, 1), 256, 0, stream>>>(
        b0, 0, 512, wq1, 0, 512, F1, 0, 512, B_ * N_, 512, 512);
    mgemm_k<128, 128, false><<<dim3(150, 4, 1), 256, 0, stream>>>(
        b0, 0, 512, wk1, 0, 512, F2, 0, 512, B_ * N_, 512, 512);

    // 3. per-head attention (fp32 SIMT: K=64)
    for (int h = 0; h < NHEADS_; ++h) {
        gemm_k<true, false><<<dim3(5, 5, B_), 256, 0, stream>>>(
            F1 + h * 64, (long)N_ * 512, 512,
            F2 + h * 64, (long)N_ * 512, 512,
            sc, SCSZ, SCLD, N_, N_, 64);
        bsoft_k<<<(SCSZ + 255) / 256, 256, 0, stream>>>(sc, mx, smv);
        colsoft_k<<<dim3(5, B_), 512, 0, stream>>>(sc, mx, smv, cond);
        gemm_k<false, false><<<dim3(5, 1, B_), 256, 0, stream>>>(
            sc, SCSZ, SCLD,
            F2 + h * 64, (long)N_ * 512, 512,
            F3 + h * 64, (long)N_ * 512, 512, N_, 64, N_);
    }
    nsoft_k<<<dim3(2, B_), 256, 0, stream>>>(F3, b1);               // x1 (bf16)

    // 4. layer-2 via MFMA: q2/k2 (bf16 out), scores2
    wtr_k<<<512, 512, 0, stream>>>(Wq_o, w2q);
    wtr_k<<<512, 512, 0, stream>>>(Wk_o, w2k);
    mgemm_k<128, 128, true><<<dim3(150, 4, 1), 256, 0, stream>>>(
        b1, 0, 512, w2q, 0, 512, b2, 0, 512, B_ * N_, 512, 512);
    mgemm_k<128, 128, true><<<dim3(150, 4, 1), 256, 0, stream>>>(
        b1, 0, 512, w2k, 0, 512, b3, 0, 512, B_ * N_, 512, 512);
    mgemm_k<64, 64, false><<<dim3(5, 5, B_), 256, 0, stream>>>(
        b2, (long)N_ * 512, 512, b3, (long)N_ * 512, 512,
        sc, SCSZ, SCLD, N_, N_, 512);
    f2b_k<<<6144, 256, 0, stream>>>(gWih, wihb, (long)2 * 1536 * 512);  // q2 dead now
    bsoft_k<<<(SCSZ + 255) / 256, 256, 0, stream>>>(sc, mx, smv);
    colsoft_k<<<dim3(5, B_), 512, 0, stream>>>(sc, mx, smv, cond);
    gemm_k<false, false, true><<<dim3(5, 8, B_), 256, 0, stream>>>(  // hp2 = att2 @ k2(bf16)
        sc, SCSZ, SCLD, (const float*)(const void*)b3, (long)N_ * 512, 512,
        F3, (long)N_ * 512, 512, N_, 512, N_);
    nsoft_k<<<dim3(2, B_), 256, 0, stream>>>(F3, b0);                // out2 (bf16)

    // 5. GRU input GEMMs via MFMA (bf16 out, layout (t, j, b))
    xrev_k<<<dim3(N_, B_), 128, 0, stream>>>(b0, seq_lens, b1);
    zero_k<<<1, 256, 0, stream>>>((float*)bar, 2048);
    mgemm_k<64, 64, true><<<dim3(24, 1, N_), 256, 0, stream>>>(      // gi_f
        wihb, 0, 512, b0, 512, (long)N_ * 512, gif, 1536 * 64, 64, 1536, 64, 512);
    mgemm_k<64, 64, true><<<dim3(24, 1, N_), 256, 0, stream>>>(      // gi_b
        wihb + 1536 * 512, 0, 512, b1, (long)B_ * 512, 512, gib, 1536 * 64, 64, 1536, 64, 512);

    // 6. recurrence (persistent, fence-free per-dir sync, full chip) + finalize
    gru_recur<<<256, 512, 0, stream>>>(gif, gib, gWhh, gbih, gbhh, seq_lens,
                                       hbuf, bar, F1, F2);
    final_k<<<38656, 256, 0, stream>>>(F1, F2, hbuf, seq_lens, out);
}